// Round 2
// 4867.945 us; speedup vs baseline: 3.0314x; 3.0314x over previous
//
#include <hip/hip_runtime.h>
#include <hip/hip_bf16.h>

#define BATCH 16384
#define WDIM 300
#define TDIM 100
#define TD2 200
#define HDIM 512
#define ESIZE 1024

typedef unsigned short ush;

__device__ __forceinline__ float bf2f(ush u) {
    union { unsigned int i; float f; } v; v.i = ((unsigned int)u) << 16; return v.f;
}
__device__ __forceinline__ float2 bf2x2(unsigned int w) {
    union { unsigned int i; float f; } a, b;
    a.i = w << 16; b.i = w & 0xffff0000u;
    return make_float2(a.f, b.f);
}
__device__ __forceinline__ ush f2bf(float f) {
    union { float f; unsigned int i; } v; v.f = f;
    unsigned int x = v.i;
    return (ush)((x + 0x7fffu + ((x >> 16) & 1u)) >> 16);
}
__device__ __forceinline__ float leaky(float v) { return v >= 0.f ? v : 0.1f * v; }

// ---------------- Kernel A2: one block per batch row, direct global dots ----------------
__global__ __launch_bounds__(256) void kA2(const int* __restrict__ x,
                                           const float* __restrict__ eW,
                                           const float* __restrict__ pdW,
                                           const float* __restrict__ pdb,
                                           float* __restrict__ cat)
{
    const int b = blockIdx.x;
    const int tt = threadIdx.x;
    if (tt >= TD2) return;
    const int half = (tt >= TDIM) ? 1 : 0;
    const int t = tt - TDIM * half;
    const int idx = x[b * 2 + half];
    const float* e = eW + (size_t)idx * WDIM;
    const float* p = pdW + (size_t)t * WDIM;
    float s = 0.f;
    for (int d = 0; d < WDIM; ++d) s += e[d] * p[d];
    cat[(size_t)b * TD2 + tt] = leaky(s + pdb[t]);
}

// ---------------- Kernel B3: 8 waves per block, one k per wave, shared cat tile ----------
// grid (B/64, 13), block 512. cS tile (51.4 KB) shared by 8 k-waves.
// LDS allows 3 blocks/CU = 24 waves/CU (75%) vs round-0's 3 waves/CU (9%).
// k forced wave-uniform via readfirstlane so comp_T rows stay on the s_load path
// (one v_fmac per MAC, SGPR operand).
__global__ __launch_bounds__(512, 4) void kB3(const float* __restrict__ cat,
                                              const float* __restrict__ compT,
                                              const float* __restrict__ clW,
                                              const float* __restrict__ clb,
                                              float* __restrict__ cv)
{
    __shared__ float cS[64][201];   // stride 201 (odd, gcd(9,32)=1) -> conflict-free
    const int tid = threadIdx.x;
    const int b0 = blockIdx.x * 64;
    const int lane = tid & 63;
    const int wid = tid >> 6;

    {   // stage 64x200 cat tile; strength-reduced row/col (no divide)
        int r = tid / TD2;
        int c = tid - r * TD2;
        for (int i = tid; i < 64 * TD2; i += 512) {
            cS[r][c] = cat[(size_t)(b0 + r) * TD2 + c];
            c += 112;                      // 512 mod 200
            if (c >= TD2) { c -= TD2; r += 3; } else { r += 2; }
        }
    }
    __syncthreads();

    int k = blockIdx.y * 8 + wid;
    if (k >= TDIM) return;                          // after the only barrier: safe
    k = __builtin_amdgcn_readfirstlane(k);          // wave-uniform -> scalar loads of T

    const float* T = compT + (size_t)k * (TD2 * TD2);
    float s = 0.f;
    for (int ch = 0; ch < 8; ++ch) {
        float cj[25];
        #pragma unroll
        for (int j = 0; j < 25; ++j) cj[j] = cS[lane][ch * 25 + j];
        for (int i = 0; i < TD2; ++i) {
            const float* Ti = T + i * TD2 + ch * 25;  // uniform across lanes -> s_load
            float u = 0.f;
            #pragma unroll
            for (int j = 0; j < 25; ++j) u += Ti[j] * cj[j];
            s += cS[lane][i] * u;
        }
    }
    float t2 = 0.f;
    const float* W = clW + (size_t)k * TD2;
    for (int j = 0; j < TD2; ++j) t2 += W[j] * cS[lane][j];
    cv[(size_t)(b0 + lane) * TDIM + k] = leaky(s + t2 + clb[k]);
}

// ---------------- Kernel C: l1 + l2 -> unnormalized out (f32!) + ssq ----------------
// grid 512 (btile=32), block 256. h bf16 in LDS; l2_W staged f32 (8-row chunks).
__global__ __launch_bounds__(256) void kC(const float* __restrict__ cv,
                                          const float* __restrict__ l1W,
                                          const float* __restrict__ l1b,
                                          const float* __restrict__ l2W,
                                          const float* __restrict__ l2b,
                                          float* __restrict__ out,
                                          float* __restrict__ ssqg)
{
    __shared__ ush hS[32 * 528];     // 33792 B
    __shared__ float w2F[8 * 516];   // 16512 B (cv tile aliased here first)
    const int tid = threadIdx.x;
    const int b0 = blockIdx.x * 32;

    float* cvS = w2F;  // 3200 floats = 12800 B <= 16512 B
    for (int i = tid; i < 3200; i += 256) cvS[i] = cv[(size_t)b0 * TDIM + i];
    __syncthreads();
    for (int o = tid; o < 32 * HDIM; o += 256) {
        int bl = o & 31, e = o >> 5;
        const float* cr = &cvS[bl * TDIM];
        const float* wr = &l1W[e * TDIM];
        float s = 0.f;
        for (int t = 0; t < TDIM; t += 4) {
            float4 w4 = *(const float4*)&wr[t];
            float4 c4 = *(const float4*)&cr[t];
            s += w4.x * c4.x + w4.y * c4.y + w4.z * c4.z + w4.w * c4.w;
        }
        s = leaky(s + l1b[e]);
        hS[bl * 528 + e] = f2bf(s);
    }
    __syncthreads();

    const int b = tid >> 3, el = tid & 7;
    float ssq = 0.f;
    for (int ec = 0; ec < 128; ++ec) {
        {   // stage 8 rows of l2_W as f32
            const float* src = l2W + (size_t)ec * 8 * HDIM;
            for (int i = tid; i < 1024; i += 256) {
                int r = i >> 7, c4 = (i & 127) * 4;
                *(float4*)&w2F[r * 516 + c4] = *(const float4*)&src[r * HDIM + c4];
            }
        }
        __syncthreads();
        {
            const ush* hr = &hS[b * 528];
            const float* wr2 = &w2F[el * 516];
            float s = 0.f;
            for (int j = 0; j < HDIM; j += 8) {
                uint4 hv = *(const uint4*)&hr[j];
                float4 w0 = *(const float4*)&wr2[j];
                float4 w1 = *(const float4*)&wr2[j + 4];
                float2 h0 = bf2x2(hv.x), h1 = bf2x2(hv.y), h2 = bf2x2(hv.z), h3 = bf2x2(hv.w);
                s += h0.x * w0.x + h0.y * w0.y + h1.x * w0.z + h1.y * w0.w
                   + h2.x * w1.x + h2.y * w1.y + h3.x * w1.z + h3.y * w1.w;
            }
            int eg = ec * 8 + el;
            float v = s + l2b[eg];
            out[(size_t)(b0 + b) * ESIZE + eg] = v;
            ssq += v * v;
        }
        __syncthreads();
    }
    ssq += __shfl_xor(ssq, 1);
    ssq += __shfl_xor(ssq, 2);
    ssq += __shfl_xor(ssq, 4);
    if (el == 0) ssqg[b0 + b] = ssq;
}

// ---------------- Kernel D: normalize f32 rows in place ----------------
// grid 8192 (2 rows each), block 256; 8 floats per thread
__global__ __launch_bounds__(256) void kD(float* __restrict__ out,
                                          const float* __restrict__ ssqg)
{
    const int tid = threadIdx.x;
    const int row = blockIdx.x * 2 + (tid >> 7);
    const int col = (tid & 127) * 8;
    const float r = rsqrtf(ssqg[row]);
    float* p = out + (size_t)row * ESIZE + col;
    float4 v0 = *(float4*)p;
    float4 v1 = *(float4*)(p + 4);
    v0.x *= r; v0.y *= r; v0.z *= r; v0.w *= r;
    v1.x *= r; v1.y *= r; v1.z *= r; v1.w *= r;
    *(float4*)p = v0;
    *(float4*)(p + 4) = v1;
}

extern "C" void kernel_launch(void* const* d_in, const int* in_sizes, int n_in,
                              void* d_out, int out_size, void* d_ws, size_t ws_size,
                              hipStream_t stream) {
    const int*   x    = (const int*)d_in[0];
    // d_in[1] = lengths (unused by reference math)
    const float* eW   = (const float*)d_in[2];
    const float* pdW  = (const float*)d_in[3];
    const float* pdb  = (const float*)d_in[4];
    const float* cT   = (const float*)d_in[5];
    const float* clW  = (const float*)d_in[6];
    const float* clb  = (const float*)d_in[7];
    const float* l1W  = (const float*)d_in[8];
    const float* l1b  = (const float*)d_in[9];
    const float* l2W  = (const float*)d_in[10];
    const float* l2b  = (const float*)d_in[11];
    float* out = (float*)d_out;

    float* cat  = (float*)d_ws;                       // B*200 f32
    float* cv   = cat + (size_t)BATCH * TD2;          // B*100 f32
    float* ssqg = cv + (size_t)BATCH * TDIM;          // B f32

    kA2<<<dim3(BATCH), dim3(256), 0, stream>>>(x, eW, pdW, pdb, cat);
    kB3<<<dim3(BATCH / 64, 13), dim3(512), 0, stream>>>(cat, cT, clW, clb, cv);
    kC<<<dim3(512), dim3(256), 0, stream>>>(cv, l1W, l1b, l2W, l2b, out, ssqg);
    kD<<<dim3(8192), dim3(256), 0, stream>>>(out, ssqg);
}

// Round 3
// 3747.878 us; speedup vs baseline: 3.9373x; 1.2989x over previous
//
#include <hip/hip_runtime.h>
#include <hip/hip_bf16.h>

#define BATCH 16384
#define WDIM 300
#define TDIM 100
#define TD2 200
#define HDIM 512
#define ESIZE 1024

typedef unsigned short ush;
typedef float f32x2 __attribute__((ext_vector_type(2)));

__device__ __forceinline__ float bf2f(ush u) {
    union { unsigned int i; float f; } v; v.i = ((unsigned int)u) << 16; return v.f;
}
__device__ __forceinline__ float2 bf2x2(unsigned int w) {
    union { unsigned int i; float f; } a, b;
    a.i = w << 16; b.i = w & 0xffff0000u;
    return make_float2(a.f, b.f);
}
__device__ __forceinline__ ush f2bf(float f) {
    union { float f; unsigned int i; } v; v.f = f;
    unsigned int x = v.i;
    return (ush)((x + 0x7fffu + ((x >> 16) & 1u)) >> 16);
}
__device__ __forceinline__ float leaky(float v) { return v >= 0.f ? v : 0.1f * v; }

// ---------------- Kernel A3: LDS-staged, coalesced embed/projdown ----------------
// grid B/16 = 1024 blocks, 256 threads. Per block: 16 batch rows -> 32 (b,half)
// embedding rows staged in LDS (coalesced float4), pdW staged in 20-row chunks.
// LDS = 32*308*4 + 20*308*4 + 128 = 64192 B -> 2 blocks/CU.
// Bank math: eS row stride 308 f32 -> start bank r*20 mod 32; 8 consecutive r
// cover all 32 banks exactly once under b128 reads -> conflict-free.
__global__ __launch_bounds__(256) void kA3(const int* __restrict__ x,
                                           const float* __restrict__ eW,
                                           const float* __restrict__ pdW,
                                           const float* __restrict__ pdb,
                                           float* __restrict__ cat)
{
    __shared__ float eS[32][308];
    __shared__ float pS[20][308];
    __shared__ int idxS[32];
    const int tid = threadIdx.x;
    const int lane = tid & 63, wv = tid >> 6;
    const int b0 = blockIdx.x * 16;

    if (tid < 32) idxS[tid] = x[b0 * 2 + tid];   // pair p: b=b0+(p>>1), h=p&1
    __syncthreads();

    // stage 32 embedding rows, coalesced per row
    for (int r = wv; r < 32; r += 4) {
        const float4* src = (const float4*)(eW + (size_t)idxS[r] * WDIM);
        for (int d = lane; d < 75; d += 64) *(float4*)&eS[r][d * 4] = src[d];
    }

    const int r = tid >> 3, tl = tid & 7;        // r: e-row (0..31), tl: t-slot
    const int t2ok = (tl + 16) < 20;             // third output valid?
    const int b = b0 + (r >> 1), h = r & 1;

    for (int tc = 0; tc < 5; ++tc) {             // 5 chunks of 20 t-rows
        __syncthreads();                         // protect pS from prev readers
        for (int i = tid; i < 1500; i += 256) {  // 20 rows x 75 float4
            int rr = i / 75, d = i - rr * 75;
            *(float4*)&pS[rr][d * 4] =
                *(const float4*)&pdW[(size_t)(tc * 20 + rr) * WDIM + d * 4];
        }
        __syncthreads();

        float a0 = 0.f, a1 = 0.f, a2 = 0.f;
        const int t2i = t2ok ? (tl + 16) : 0;    // clamped (discarded if invalid)
        for (int d = 0; d < 75; ++d) {
            float4 e4 = *(const float4*)&eS[r][d * 4];
            float4 p0 = *(const float4*)&pS[tl][d * 4];
            float4 p1 = *(const float4*)&pS[tl + 8][d * 4];
            float4 p2 = *(const float4*)&pS[t2i][d * 4];
            a0 += e4.x * p0.x + e4.y * p0.y + e4.z * p0.z + e4.w * p0.w;
            a1 += e4.x * p1.x + e4.y * p1.y + e4.z * p1.z + e4.w * p1.w;
            a2 += e4.x * p2.x + e4.y * p2.y + e4.z * p2.z + e4.w * p2.w;
        }
        {
            int t = tc * 20 + tl;
            cat[(size_t)b * TD2 + h * 100 + t] = leaky(a0 + pdb[t]);
            t += 8;
            cat[(size_t)b * TD2 + h * 100 + t] = leaky(a1 + pdb[t]);
            if (t2ok) {
                t += 8;
                cat[(size_t)b * TD2 + h * 100 + t] = leaky(a2 + pdb[t]);
            }
        }
    }
}

// ---------------- Kernel B4: packed-f32 trilinear, 8 k-waves share cat tile ----------
// grid (B/64, 13), block 512. LDS 51.4KB -> 3 blocks/CU = 24 waves/CU.
// Inner MACs via v_pk_fma_f32 (inline asm): T row chunk in SGPR pairs (s_load,
// k wave-uniform via readfirstlane), cat pairs in VGPR pairs. Halves VALU issue
// count vs scalar v_fmac and halves the outer cS ds_read count. Bit-exact f32.
__global__ __launch_bounds__(512, 6) void kB4(const float* __restrict__ cat,
                                              const float* __restrict__ compT,
                                              const float* __restrict__ clW,
                                              const float* __restrict__ clb,
                                              float* __restrict__ cv)
{
    __shared__ float cS[64][201];   // stride 201 (odd) -> conflict-free
    const int tid = threadIdx.x;
    const int b0 = blockIdx.x * 64;
    const int lane = tid & 63;
    const int wid = tid >> 6;

    {   // stage 64x200 cat tile; strength-reduced row/col (no divide)
        int r = tid / TD2;
        int c = tid - r * TD2;
        for (int i = tid; i < 64 * TD2; i += 512) {
            cS[r][c] = cat[(size_t)(b0 + r) * TD2 + c];
            c += 112;                      // 512 mod 200
            if (c >= TD2) { c -= TD2; r += 3; } else { r += 2; }
        }
    }
    __syncthreads();

    int k = blockIdx.y * 8 + wid;
    if (k >= TDIM) return;                          // after the only barrier: safe
    k = __builtin_amdgcn_readfirstlane(k);          // wave-uniform -> scalar loads of T

    const float* T = compT + (size_t)k * (TD2 * TD2);
    float s = 0.f;
    for (int ch = 0; ch < 4; ++ch) {
        const int c0 = ch * 50;
        f32x2 cj2[25];
        #pragma unroll
        for (int j = 0; j < 25; ++j) {
            f32x2 c2; c2.x = cS[lane][c0 + 2 * j]; c2.y = cS[lane][c0 + 2 * j + 1];
            cj2[j] = c2;
        }
        for (int i = 0; i < TD2; ++i) {
            const f32x2* T2 = (const f32x2*)(T + (size_t)i * TD2 + c0); // uniform
            f32x2 trow[25];
            #pragma unroll
            for (int j = 0; j < 25; ++j) trow[j] = T2[j];   // batched s_loads
            f32x2 u2; u2.x = 0.f; u2.y = 0.f;
            #pragma unroll
            for (int j = 0; j < 25; ++j) {
                asm("v_pk_fma_f32 %0, %1, %2, %0"
                    : "+v"(u2) : "s"(trow[j]), "v"(cj2[j]));
            }
            s += cS[lane][i] * (u2.x + u2.y);
        }
    }
    float t2 = 0.f;
    const float* W = clW + (size_t)k * TD2;
    for (int j = 0; j < TD2; ++j) t2 += W[j] * cS[lane][j];
    cv[(size_t)(b0 + lane) * TDIM + k] = leaky(s + t2 + clb[k]);
}

// ---------------- Kernel C: l1 + l2 -> unnormalized out (f32!) + ssq ----------------
// grid 512 (btile=32), block 256. h bf16 in LDS; l2_W staged f32 (8-row chunks).
__global__ __launch_bounds__(256) void kC(const float* __restrict__ cv,
                                          const float* __restrict__ l1W,
                                          const float* __restrict__ l1b,
                                          const float* __restrict__ l2W,
                                          const float* __restrict__ l2b,
                                          float* __restrict__ out,
                                          float* __restrict__ ssqg)
{
    __shared__ ush hS[32 * 528];     // 33792 B
    __shared__ float w2F[8 * 516];   // 16512 B (cv tile aliased here first)
    const int tid = threadIdx.x;
    const int b0 = blockIdx.x * 32;

    float* cvS = w2F;  // 3200 floats = 12800 B <= 16512 B
    for (int i = tid; i < 3200; i += 256) cvS[i] = cv[(size_t)b0 * TDIM + i];
    __syncthreads();
    for (int o = tid; o < 32 * HDIM; o += 256) {
        int bl = o & 31, e = o >> 5;
        const float* cr = &cvS[bl * TDIM];
        const float* wr = &l1W[e * TDIM];
        float s = 0.f;
        for (int t = 0; t < TDIM; t += 4) {
            float4 w4 = *(const float4*)&wr[t];
            float4 c4 = *(const float4*)&cr[t];
            s += w4.x * c4.x + w4.y * c4.y + w4.z * c4.z + w4.w * c4.w;
        }
        s = leaky(s + l1b[e]);
        hS[bl * 528 + e] = f2bf(s);
    }
    __syncthreads();

    const int b = tid >> 3, el = tid & 7;
    float ssq = 0.f;
    for (int ec = 0; ec < 128; ++ec) {
        {   // stage 8 rows of l2_W as f32
            const float* src = l2W + (size_t)ec * 8 * HDIM;
            for (int i = tid; i < 1024; i += 256) {
                int r = i >> 7, c4 = (i & 127) * 4;
                *(float4*)&w2F[r * 516 + c4] = *(const float4*)&src[r * HDIM + c4];
            }
        }
        __syncthreads();
        {
            const ush* hr = &hS[b * 528];
            const float* wr2 = &w2F[el * 516];
            float s = 0.f;
            for (int j = 0; j < HDIM; j += 8) {
                uint4 hv = *(const uint4*)&hr[j];
                float4 w0 = *(const float4*)&wr2[j];
                float4 w1 = *(const float4*)&wr2[j + 4];
                float2 h0 = bf2x2(hv.x), h1 = bf2x2(hv.y), h2 = bf2x2(hv.z), h3 = bf2x2(hv.w);
                s += h0.x * w0.x + h0.y * w0.y + h1.x * w0.z + h1.y * w0.w
                   + h2.x * w1.x + h2.y * w1.y + h3.x * w1.z + h3.y * w1.w;
            }
            int eg = ec * 8 + el;
            float v = s + l2b[eg];
            out[(size_t)(b0 + b) * ESIZE + eg] = v;
            ssq += v * v;
        }
        __syncthreads();
    }
    ssq += __shfl_xor(ssq, 1);
    ssq += __shfl_xor(ssq, 2);
    ssq += __shfl_xor(ssq, 4);
    if (el == 0) ssqg[b0 + b] = ssq;
}

// ---------------- Kernel D: normalize f32 rows in place ----------------
// grid 8192 (2 rows each), block 256; 8 floats per thread
__global__ __launch_bounds__(256) void kD(float* __restrict__ out,
                                          const float* __restrict__ ssqg)
{
    const int tid = threadIdx.x;
    const int row = blockIdx.x * 2 + (tid >> 7);
    const int col = (tid & 127) * 8;
    const float r = rsqrtf(ssqg[row]);
    float* p = out + (size_t)row * ESIZE + col;
    float4 v0 = *(float4*)p;
    float4 v1 = *(float4*)(p + 4);
    v0.x *= r; v0.y *= r; v0.z *= r; v0.w *= r;
    v1.x *= r; v1.y *= r; v1.z *= r; v1.w *= r;
    *(float4*)p = v0;
    *(float4*)(p + 4) = v1;
}

extern "C" void kernel_launch(void* const* d_in, const int* in_sizes, int n_in,
                              void* d_out, int out_size, void* d_ws, size_t ws_size,
                              hipStream_t stream) {
    const int*   x    = (const int*)d_in[0];
    // d_in[1] = lengths (unused by reference math)
    const float* eW   = (const float*)d_in[2];
    const float* pdW  = (const float*)d_in[3];
    const float* pdb  = (const float*)d_in[4];
    const float* cT   = (const float*)d_in[5];
    const float* clW  = (const float*)d_in[6];
    const float* clb  = (const float*)d_in[7];
    const float* l1W  = (const float*)d_in[8];
    const float* l1b  = (const float*)d_in[9];
    const float* l2W  = (const float*)d_in[10];
    const float* l2b  = (const float*)d_in[11];
    float* out = (float*)d_out;

    float* cat  = (float*)d_ws;                       // B*200 f32
    float* cv   = cat + (size_t)BATCH * TD2;          // B*100 f32
    float* ssqg = cv + (size_t)BATCH * TDIM;          // B f32

    kA3<<<dim3(BATCH / 16), dim3(256), 0, stream>>>(x, eW, pdW, pdb, cat);
    kB4<<<dim3(BATCH / 64, 13), dim3(512), 0, stream>>>(cat, cT, clW, clb, cv);
    kC<<<dim3(512), dim3(256), 0, stream>>>(cv, l1W, l1b, l2W, l2b, out, ssqg);
    kD<<<dim3(8192), dim3(256), 0, stream>>>(out, ssqg);
}

// Round 4
// 3457.916 us; speedup vs baseline: 4.2675x; 1.0839x over previous
//
#include <hip/hip_runtime.h>
#include <hip/hip_bf16.h>

#define BATCH 16384
#define WDIM 300
#define TDIM 100
#define TD2 200
#define HDIM 512
#define ESIZE 1024

// padded T geometry for MFMA path
#define TI 224           // i rows: 200 real + 1 clW row + zero pad (14 tiles of 16)
#define TJ 224           // j cols: 200 real + zero pad (7 chunks of 32)
#define KSLICE (TI * TJ) // 50176 elems per k
#define CSTR 232         // LDS C row stride in bf16 elems (464 B: 16B-aligned, 2-way banks)

typedef unsigned short ush;
typedef float f32x2 __attribute__((ext_vector_type(2)));
typedef float f32x4 __attribute__((ext_vector_type(4)));
typedef short bf16x8 __attribute__((ext_vector_type(8)));   // guide-verified MFMA frag type

__device__ __forceinline__ float bf2f(ush u) {
    union { unsigned int i; float f; } v; v.i = ((unsigned int)u) << 16; return v.f;
}
__device__ __forceinline__ float2 bf2x2(unsigned int w) {
    union { unsigned int i; float f; } a, b;
    a.i = w << 16; b.i = w & 0xffff0000u;
    return make_float2(a.f, b.f);
}
__device__ __forceinline__ ush f2bf(float f) {
    union { float f; unsigned int i; } v; v.f = f;
    unsigned int x = v.i;
    return (ush)((x + 0x7fffu + ((x >> 16) & 1u)) >> 16);
}
__device__ __forceinline__ float leaky(float v) { return v >= 0.f ? v : 0.1f * v; }

// ---------------- Kernel A3: LDS-staged, coalesced embed/projdown ----------------
__global__ __launch_bounds__(256) void kA3(const int* __restrict__ x,
                                           const float* __restrict__ eW,
                                           const float* __restrict__ pdW,
                                           const float* __restrict__ pdb,
                                           float* __restrict__ cat)
{
    __shared__ float eS[32][308];
    __shared__ float pS[20][308];
    __shared__ int idxS[32];
    const int tid = threadIdx.x;
    const int lane = tid & 63, wv = tid >> 6;
    const int b0 = blockIdx.x * 16;

    if (tid < 32) idxS[tid] = x[b0 * 2 + tid];
    __syncthreads();

    for (int r = wv; r < 32; r += 4) {
        const float4* src = (const float4*)(eW + (size_t)idxS[r] * WDIM);
        for (int d = lane; d < 75; d += 64) *(float4*)&eS[r][d * 4] = src[d];
    }

    const int r = tid >> 3, tl = tid & 7;
    const int t2ok = (tl + 16) < 20;
    const int b = b0 + (r >> 1), h = r & 1;

    for (int tc = 0; tc < 5; ++tc) {
        __syncthreads();
        for (int i = tid; i < 1500; i += 256) {
            int rr = i / 75, d = i - rr * 75;
            *(float4*)&pS[rr][d * 4] =
                *(const float4*)&pdW[(size_t)(tc * 20 + rr) * WDIM + d * 4];
        }
        __syncthreads();

        float a0 = 0.f, a1 = 0.f, a2 = 0.f;
        const int t2i = t2ok ? (tl + 16) : 0;
        for (int d = 0; d < 75; ++d) {
            float4 e4 = *(const float4*)&eS[r][d * 4];
            float4 p0 = *(const float4*)&pS[tl][d * 4];
            float4 p1 = *(const float4*)&pS[tl + 8][d * 4];
            float4 p2 = *(const float4*)&pS[t2i][d * 4];
            a0 += e4.x * p0.x + e4.y * p0.y + e4.z * p0.z + e4.w * p0.w;
            a1 += e4.x * p1.x + e4.y * p1.y + e4.z * p1.z + e4.w * p1.w;
            a2 += e4.x * p2.x + e4.y * p2.y + e4.z * p2.z + e4.w * p2.w;
        }
        {
            int t = tc * 20 + tl;
            cat[(size_t)b * TD2 + h * 100 + t] = leaky(a0 + pdb[t]);
            t += 8;
            cat[(size_t)b * TD2 + h * 100 + t] = leaky(a1 + pdb[t]);
            if (t2ok) {
                t += 8;
                cat[(size_t)b * TD2 + h * 100 + t] = leaky(a2 + pdb[t]);
            }
        }
    }
}

// ---------------- Kernel T: precompute split-bf16 padded T (+clW as row 200) ----------
// grid (100, 7), block 256. Tpad[k][i][j]: i<200 = T_k; i==200 = clW[k]; else 0.
// j>=200 zero. hi = rne(x); lo = rne(x - f32(hi)) -> x within ~2^-16 rel.
__global__ __launch_bounds__(256) void kT(const float* __restrict__ compT,
                                          const float* __restrict__ clW,
                                          ush* __restrict__ Thi,
                                          ush* __restrict__ Tlo)
{
    const int k = blockIdx.x;
    const int r0 = blockIdx.y * 32;
    const int j = threadIdx.x;
    if (j >= TJ) return;
    for (int i = r0; i < r0 + 32; ++i) {
        float v = 0.f;
        if (j < 200) {
            if (i < 200) v = compT[((size_t)k * 200 + i) * 200 + j];
            else if (i == 200) v = clW[(size_t)k * 200 + j];
        }
        ush hi = f2bf(v);
        ush lo = f2bf(v - bf2f(hi));
        size_t o = (size_t)k * KSLICE + (size_t)i * TJ + j;
        Thi[o] = hi;
        Tlo[o] = lo;
    }
}

// ---------------- Kernel B5: MFMA split-bf16 trilinear ----------------
// grid 256 blocks (64 batch rows each), 512 threads = 8 waves, 1 block/CU.
// GEMM per k: D[i,b] = sum_j Tpad_k[i,j] * C[b,j], split-bf16 3-term MFMA
// (ThiChi + ThiClo + TloChi). i covers 14 tiles incl. the clW row (term2 free).
// Waves: 2 k-streams x 4 i-tile groups {4,4,3,3}; SIMD pairing (m = w+2s mod 4)
// gives perfectly balanced 7 tile-units per SIMD. No barriers in the k-loop:
// A frags per-wave-unique from global (16B/lane, full-line coalesced), B frags
// from LDS C-tile, partial row-dots go to global `part` (combined in kB5b).
template<int NT, int TB>
__device__ __forceinline__ void kb5_work(const ush (*__restrict__ Chi)[CSTR],
                                         const ush (*__restrict__ Clo)[CSTR],
                                         const ush* __restrict__ Thi,
                                         const ush* __restrict__ Tlo,
                                         float* __restrict__ part,
                                         int lane, int s, int m, int b0)
{
    const int rg = lane >> 4, cl = lane & 15;
    // consume weights C[b][i] (i==200 -> 1.0 for the clW row; pad -> 0)
    float cval[NT][4][4];
    #pragma unroll
    for (int it = 0; it < NT; ++it)
        #pragma unroll
        for (int bt = 0; bt < 4; ++bt)
            #pragma unroll
            for (int r = 0; r < 4; ++r) {
                int i = (TB + it) * 16 + rg * 4 + r;
                int b = bt * 16 + cl;
                float v;
                if (i < 200) v = bf2f(Chi[b][i]) + bf2f(Clo[b][i]);
                else v = (i == 200) ? 1.f : 0.f;
                cval[it][bt][r] = v;
            }
    int rbase[NT];
    #pragma unroll
    for (int it = 0; it < NT; ++it)
        rbase[it] = ((TB + it) * 16 + cl) * TJ + rg * 8;

    for (int t = 0; t < 50; ++t) {
        const int k = 2 * t + s;
        const ush* Th = Thi + (size_t)k * KSLICE;
        const ush* Tl = Tlo + (size_t)k * KSLICE;
        f32x4 acc[NT][4];
        #pragma unroll
        for (int it = 0; it < NT; ++it)
            #pragma unroll
            for (int bt = 0; bt < 4; ++bt)
                acc[it][bt] = (f32x4){0.f, 0.f, 0.f, 0.f};

        #pragma unroll
        for (int jc = 0; jc < 7; ++jc) {
            bf16x8 ah[NT], al[NT];
            #pragma unroll
            for (int it = 0; it < NT; ++it) {
                ah[it] = *(const bf16x8*)(Th + rbase[it] + jc * 32);
                al[it] = *(const bf16x8*)(Tl + rbase[it] + jc * 32);
            }
            bf16x8 bh[4], blo[4];
            #pragma unroll
            for (int bt = 0; bt < 4; ++bt) {
                const int boff = jc * 32 + rg * 8;
                bh[bt]  = *(const bf16x8*)&Chi[bt * 16 + cl][boff];
                blo[bt] = *(const bf16x8*)&Clo[bt * 16 + cl][boff];
            }
            #pragma unroll
            for (int it = 0; it < NT; ++it)
                #pragma unroll
                for (int bt = 0; bt < 4; ++bt) {
                    acc[it][bt] = __builtin_amdgcn_mfma_f32_16x16x32_bf16(ah[it], bh[bt],  acc[it][bt], 0, 0, 0);
                    acc[it][bt] = __builtin_amdgcn_mfma_f32_16x16x32_bf16(ah[it], blo[bt], acc[it][bt], 0, 0, 0);
                    acc[it][bt] = __builtin_amdgcn_mfma_f32_16x16x32_bf16(al[it], bh[bt],  acc[it][bt], 0, 0, 0);
                }
        }
        // consume: p[bt] = sum_i C[b,i] * D[i,b] over this wave's i-tiles
        float p[4];
        #pragma unroll
        for (int bt = 0; bt < 4; ++bt) {
            float v = 0.f;
            #pragma unroll
            for (int it = 0; it < NT; ++it)
                #pragma unroll
                for (int r = 0; r < 4; ++r)
                    v += acc[it][bt][r] * cval[it][bt][r];
            v += __shfl_xor(v, 16);
            v += __shfl_xor(v, 32);
            p[bt] = v;
        }
        if (lane < 16) {
            #pragma unroll
            for (int bt = 0; bt < 4; ++bt)
                part[((size_t)(m * 100 + k) << 14) + b0 + bt * 16 + lane] = p[bt];
        }
    }
}

__global__ __launch_bounds__(512, 2) void kB5(const float* __restrict__ cat,
                                              const ush* __restrict__ Thi,
                                              const ush* __restrict__ Tlo,
                                              float* __restrict__ part)
{
    __shared__ ush Chi[64][CSTR];   // 2*64*232*2 = 59392 B total
    __shared__ ush Clo[64][CSTR];
    const int tid = threadIdx.x;
    const int b0 = blockIdx.x * 64;
    const int lane = tid & 63, w = tid >> 6;

    {   // stage C tile as split-bf16; zero the j-pad
        const int r = tid >> 3, tl = tid & 7;
        const float* src = cat + (size_t)(b0 + r) * TD2;
        for (int c = tl; c < CSTR; c += 8) {
            float v = (c < 200) ? src[c] : 0.f;
            ush hi = f2bf(v);
            Chi[r][c] = hi;
            Clo[r][c] = f2bf(v - bf2f(hi));
        }
    }
    __syncthreads();

    const int s = w >> 2;
    const int m = (w + 2 * s) & 3;   // SIMD pairing: {4,3} tile-units per SIMD
    if (m == 0)      kb5_work<4, 0 >(Chi, Clo, Thi, Tlo, part, lane, s, m, b0);
    else if (m == 1) kb5_work<4, 4 >(Chi, Clo, Thi, Tlo, part, lane, s, m, b0);
    else if (m == 2) kb5_work<3, 8 >(Chi, Clo, Thi, Tlo, part, lane, s, m, b0);
    else             kb5_work<3, 11>(Chi, Clo, Thi, Tlo, part, lane, s, m, b0);
}

// ---------------- Kernel B5b: combine 4 partials + clb + leaky -> cv[k][b] ----------
__global__ __launch_bounds__(256) void kB5b(const float* __restrict__ part,
                                            const float* __restrict__ clb,
                                            float* __restrict__ cv)
{
    const int idx = blockIdx.x * 256 + threadIdx.x;
    const int b = idx & (BATCH - 1);
    const int k = idx >> 14;
    float s = part[((size_t)(0 * 100 + k) << 14) + b]
            + part[((size_t)(1 * 100 + k) << 14) + b]
            + part[((size_t)(2 * 100 + k) << 14) + b]
            + part[((size_t)(3 * 100 + k) << 14) + b];
    cv[(size_t)k * BATCH + b] = leaky(s + clb[k]);
}

// ---------------- Kernel B4 (fallback if ws too small): packed-f32 trilinear --------
// writes cv in [k][b] layout to match kC.
__global__ __launch_bounds__(512, 6) void kB4(const float* __restrict__ cat,
                                              const float* __restrict__ compT,
                                              const float* __restrict__ clW,
                                              const float* __restrict__ clb,
                                              float* __restrict__ cv)
{
    __shared__ float cS[64][201];
    const int tid = threadIdx.x;
    const int b0 = blockIdx.x * 64;
    const int lane = tid & 63;
    const int wid = tid >> 6;

    {
        int r = tid / TD2;
        int c = tid - r * TD2;
        for (int i = tid; i < 64 * TD2; i += 512) {
            cS[r][c] = cat[(size_t)(b0 + r) * TD2 + c];
            c += 112;
            if (c >= TD2) { c -= TD2; r += 3; } else { r += 2; }
        }
    }
    __syncthreads();

    int k = blockIdx.y * 8 + wid;
    if (k >= TDIM) return;
    k = __builtin_amdgcn_readfirstlane(k);

    const float* T = compT + (size_t)k * (TD2 * TD2);
    float s = 0.f;
    for (int ch = 0; ch < 4; ++ch) {
        const int c0 = ch * 50;
        f32x2 cj2[25];
        #pragma unroll
        for (int j = 0; j < 25; ++j) {
            f32x2 c2; c2.x = cS[lane][c0 + 2 * j]; c2.y = cS[lane][c0 + 2 * j + 1];
            cj2[j] = c2;
        }
        for (int i = 0; i < TD2; ++i) {
            const f32x2* T2 = (const f32x2*)(T + (size_t)i * TD2 + c0);
            f32x2 trow[25];
            #pragma unroll
            for (int j = 0; j < 25; ++j) trow[j] = T2[j];
            f32x2 u2; u2.x = 0.f; u2.y = 0.f;
            #pragma unroll
            for (int j = 0; j < 25; ++j) {
                asm("v_pk_fma_f32 %0, %1, %2, %0"
                    : "+v"(u2) : "s"(trow[j]), "v"(cj2[j]));
            }
            s += cS[lane][i] * (u2.x + u2.y);
        }
    }
    float t2 = 0.f;
    const float* W = clW + (size_t)k * TD2;
    for (int j = 0; j < TD2; ++j) t2 += W[j] * cS[lane][j];
    cv[(size_t)k * BATCH + b0 + lane] = leaky(s + t2 + clb[k]);
}

// ---------------- Kernel C: l1 + l2 -> unnormalized out (f32) + ssq ----------------
// reads cv in [k][b] layout.
__global__ __launch_bounds__(256) void kC(const float* __restrict__ cv,
                                          const float* __restrict__ l1W,
                                          const float* __restrict__ l1b,
                                          const float* __restrict__ l2W,
                                          const float* __restrict__ l2b,
                                          float* __restrict__ out,
                                          float* __restrict__ ssqg)
{
    __shared__ ush hS[32 * 528];     // 33792 B
    __shared__ float w2F[8 * 516];   // 16512 B (cv tile aliased here first)
    const int tid = threadIdx.x;
    const int b0 = blockIdx.x * 32;

    float* cvS = w2F;  // 3200 floats
    for (int i = tid; i < 3200; i += 256) {
        int k = i >> 5, bl = i & 31;
        cvS[bl * TDIM + k] = cv[(size_t)k * BATCH + b0 + bl];
    }
    __syncthreads();
    for (int o = tid; o < 32 * HDIM; o += 256) {
        int bl = o & 31, e = o >> 5;
        const float* cr = &cvS[bl * TDIM];
        const float* wr = &l1W[e * TDIM];
        float s = 0.f;
        for (int t = 0; t < TDIM; t += 4) {
            float4 w4 = *(const float4*)&wr[t];
            float4 c4 = *(const float4*)&cr[t];
            s += w4.x * c4.x + w4.y * c4.y + w4.z * c4.z + w4.w * c4.w;
        }
        s = leaky(s + l1b[e]);
        hS[bl * 528 + e] = f2bf(s);
    }
    __syncthreads();

    const int b = tid >> 3, el = tid & 7;
    float ssq = 0.f;
    for (int ec = 0; ec < 128; ++ec) {
        {
            const float* src = l2W + (size_t)ec * 8 * HDIM;
            for (int i = tid; i < 1024; i += 256) {
                int r = i >> 7, c4 = (i & 127) * 4;
                *(float4*)&w2F[r * 516 + c4] = *(const float4*)&src[r * HDIM + c4];
            }
        }
        __syncthreads();
        {
            const ush* hr = &hS[b * 528];
            const float* wr2 = &w2F[el * 516];
            float s = 0.f;
            for (int j = 0; j < HDIM; j += 8) {
                uint4 hv = *(const uint4*)&hr[j];
                float4 w0 = *(const float4*)&wr2[j];
                float4 w1 = *(const float4*)&wr2[j + 4];
                float2 h0 = bf2x2(hv.x), h1 = bf2x2(hv.y), h2 = bf2x2(hv.z), h3 = bf2x2(hv.w);
                s += h0.x * w0.x + h0.y * w0.y + h1.x * w0.z + h1.y * w0.w
                   + h2.x * w1.x + h2.y * w1.y + h3.x * w1.z + h3.y * w1.w;
            }
            int eg = ec * 8 + el;
            float v = s + l2b[eg];
            out[(size_t)(b0 + b) * ESIZE + eg] = v;
            ssq += v * v;
        }
        __syncthreads();
    }
    ssq += __shfl_xor(ssq, 1);
    ssq += __shfl_xor(ssq, 2);
    ssq += __shfl_xor(ssq, 4);
    if (el == 0) ssqg[b0 + b] = ssq;
}

// ---------------- Kernel D: normalize f32 rows in place ----------------
__global__ __launch_bounds__(256) void kD(float* __restrict__ out,
                                          const float* __restrict__ ssqg)
{
    const int tid = threadIdx.x;
    const int row = blockIdx.x * 2 + (tid >> 7);
    const int col = (tid & 127) * 8;
    const float r = rsqrtf(ssqg[row]);
    float* p = out + (size_t)row * ESIZE + col;
    float4 v0 = *(float4*)p;
    float4 v1 = *(float4*)(p + 4);
    v0.x *= r; v0.y *= r; v0.z *= r; v0.w *= r;
    v1.x *= r; v1.y *= r; v1.z *= r; v1.w *= r;
    *(float4*)p = v0;
    *(float4*)(p + 4) = v1;
}

extern "C" void kernel_launch(void* const* d_in, const int* in_sizes, int n_in,
                              void* d_out, int out_size, void* d_ws, size_t ws_size,
                              hipStream_t stream) {
    const int*   x    = (const int*)d_in[0];
    const float* eW   = (const float*)d_in[2];
    const float* pdW  = (const float*)d_in[3];
    const float* pdb  = (const float*)d_in[4];
    const float* cT   = (const float*)d_in[5];
    const float* clW  = (const float*)d_in[6];
    const float* clb  = (const float*)d_in[7];
    const float* l1W  = (const float*)d_in[8];
    const float* l1b  = (const float*)d_in[9];
    const float* l2W  = (const float*)d_in[10];
    const float* l2b  = (const float*)d_in[11];
    float* out = (float*)d_out;

    // workspace layout
    const size_t catN  = (size_t)BATCH * TD2;            // f32
    const size_t cvN   = (size_t)BATCH * TDIM;           // f32
    const size_t ssqN  = (size_t)BATCH;                  // f32
    const size_t tpadN = (size_t)TDIM * KSLICE;          // ush each (hi, lo)
    const size_t partN = (size_t)4 * TDIM * BATCH;       // f32

    float* cat  = (float*)d_ws;
    float* cv   = cat + catN;
    float* ssqg = cv + cvN;
    ush*   Thi  = (ush*)(ssqg + ssqN);
    ush*   Tlo  = Thi + tpadN;
    float* part = (float*)(Tlo + tpadN);

    const size_t need = (catN + cvN + ssqN + partN) * 4 + tpadN * 2 * 2;

    kA3<<<dim3(BATCH / 16), dim3(256), 0, stream>>>(x, eW, pdW, pdb, cat);
    if (ws_size >= need) {
        kT  <<<dim3(TDIM, TI / 32), dim3(256), 0, stream>>>(cT, clW, Thi, Tlo);
        kB5 <<<dim3(BATCH / 64), dim3(512), 0, stream>>>(cat, Thi, Tlo, part);
        kB5b<<<dim3(BATCH * TDIM / 256), dim3(256), 0, stream>>>(part, clb, cv);
    } else {
        kB4<<<dim3(BATCH / 64, 13), dim3(512), 0, stream>>>(cat, cT, clW, clb, cv);
    }
    kC<<<dim3(512), dim3(256), 0, stream>>>(cv, l1W, l1b, l2W, l2b, out, ssqg);
    kD<<<dim3(8192), dim3(256), 0, stream>>>(out, ssqg);
}

// Round 5
// 3017.199 us; speedup vs baseline: 4.8909x; 1.1461x over previous
//
#include <hip/hip_runtime.h>
#include <hip/hip_bf16.h>

#define BATCH 16384
#define WDIM 300
#define TDIM 100
#define TD2 200
#define HDIM 512
#define ESIZE 1024

// fp16 MFMA path geometry
#define NIT 13            // i-tiles of 16: 208 rows = 200 real + clW row + 7 zero pad
#define NJC 7             // j-chunks of 32: 224 = 200 real + 24 zero pad
#define CSTR 232          // LDS C row stride in fp16 elems (464 B: 16B-aligned, ~2-way banks)
#define KQ 4              // k-split groups
#define KPQ 25            // k per group

typedef unsigned short ush;
typedef float f32x2 __attribute__((ext_vector_type(2)));
typedef float f32x4 __attribute__((ext_vector_type(4)));
typedef _Float16 f16x8 __attribute__((ext_vector_type(8)));

__device__ __forceinline__ float bf2f(ush u) {
    union { unsigned int i; float f; } v; v.i = ((unsigned int)u) << 16; return v.f;
}
__device__ __forceinline__ float2 bf2x2(unsigned int w) {
    union { unsigned int i; float f; } a, b;
    a.i = w << 16; b.i = w & 0xffff0000u;
    return make_float2(a.f, b.f);
}
__device__ __forceinline__ ush f2bf(float f) {
    union { float f; unsigned int i; } v; v.f = f;
    unsigned int x = v.i;
    return (ush)((x + 0x7fffu + ((x >> 16) & 1u)) >> 16);
}
__device__ __forceinline__ float leaky(float v) { return v >= 0.f ? v : 0.1f * v; }

// ---------------- Kernel A3: LDS-staged, coalesced embed/projdown ----------------
__global__ __launch_bounds__(256) void kA3(const int* __restrict__ x,
                                           const float* __restrict__ eW,
                                           const float* __restrict__ pdW,
                                           const float* __restrict__ pdb,
                                           float* __restrict__ cat)
{
    __shared__ float eS[32][308];
    __shared__ float pS[20][308];
    __shared__ int idxS[32];
    const int tid = threadIdx.x;
    const int lane = tid & 63, wv = tid >> 6;
    const int b0 = blockIdx.x * 16;

    if (tid < 32) idxS[tid] = x[b0 * 2 + tid];
    __syncthreads();

    for (int r = wv; r < 32; r += 4) {
        const float4* src = (const float4*)(eW + (size_t)idxS[r] * WDIM);
        for (int d = lane; d < 75; d += 64) *(float4*)&eS[r][d * 4] = src[d];
    }

    const int r = tid >> 3, tl = tid & 7;
    const int t2ok = (tl + 16) < 20;
    const int b = b0 + (r >> 1), h = r & 1;

    for (int tc = 0; tc < 5; ++tc) {
        __syncthreads();
        for (int i = tid; i < 1500; i += 256) {
            int rr = i / 75, d = i - rr * 75;
            *(float4*)&pS[rr][d * 4] =
                *(const float4*)&pdW[(size_t)(tc * 20 + rr) * WDIM + d * 4];
        }
        __syncthreads();

        float a0 = 0.f, a1 = 0.f, a2 = 0.f;
        const int t2i = t2ok ? (tl + 16) : 0;
        for (int d = 0; d < 75; ++d) {
            float4 e4 = *(const float4*)&eS[r][d * 4];
            float4 p0 = *(const float4*)&pS[tl][d * 4];
            float4 p1 = *(const float4*)&pS[tl + 8][d * 4];
            float4 p2 = *(const float4*)&pS[t2i][d * 4];
            a0 += e4.x * p0.x + e4.y * p0.y + e4.z * p0.z + e4.w * p0.w;
            a1 += e4.x * p1.x + e4.y * p1.y + e4.z * p1.z + e4.w * p1.w;
            a2 += e4.x * p2.x + e4.y * p2.y + e4.z * p2.z + e4.w * p2.w;
        }
        {
            int t = tc * 20 + tl;
            cat[(size_t)b * TD2 + h * 100 + t] = leaky(a0 + pdb[t]);
            t += 8;
            cat[(size_t)b * TD2 + h * 100 + t] = leaky(a1 + pdb[t]);
            if (t2ok) {
                t += 8;
                cat[(size_t)b * TD2 + h * 100 + t] = leaky(a2 + pdb[t]);
            }
        }
    }
}

// ---------------- Kernel T: build fragment-ordered fp16 T' ----------------
// grid (100, 13), block 448 = 7 jc * 64 lanes. T'[(k*13+it)*7+jc][lane][8]:
// lane (cl=lane&15, rg=lane>>4) holds Tpad[i=it*16+cl][j=jc*32+rg*8 + 0..7],
// where Tpad: i<200 = comp_T[k], i==200 = clW[k], else 0; j>=200 zero.
// Each thread stores 16B contiguous -> fully coalesced; kB6 A-loads are 1KB/wave.
__global__ __launch_bounds__(448) void kT(const float* __restrict__ compT,
                                          const float* __restrict__ clW,
                                          ush* __restrict__ Tp)
{
    const int k = blockIdx.x, it = blockIdx.y;
    const int jc = threadIdx.x >> 6, lane = threadIdx.x & 63;
    const int i = it * 16 + (lane & 15);
    const int j0 = jc * 32 + (lane >> 4) * 8;
    ush vals[8];
    #pragma unroll
    for (int e = 0; e < 8; ++e) {
        int j = j0 + e;
        float v = 0.f;
        if (j < 200) {
            if (i < 200) v = compT[((size_t)k * 200 + i) * 200 + j];
            else if (i == 200) v = clW[(size_t)k * 200 + j];
        }
        union { _Float16 h; ush u; } cvt; cvt.h = (_Float16)v; vals[e] = cvt.u;
    }
    size_t o = (((size_t)k * NIT + it) * NJC + jc) * 64 + lane;   // 16B units
    ((uint4*)Tp)[o] = *(const uint4*)vals;
}

// ---------------- Kernel B6: fp16 MFMA trilinear, 128-row tiles, k-split 4 ------
// grid 512 flat (128 b-chunks x 4 k-quarters via XCD-aware mapping), block 512
// = 8 waves. LDS: C fp16 [128][232] (59.4KB) + pRed[25][128] f32 (12.8KB) =
// 72.2KB -> 2 blocks/CU (16 waves/CU). Waves own i-tiles {2,2,2,2,2,1,1,1};
// all 13 tiles complete in-block -> cv written directly (no part buffer).
// Per-block T traffic = 25k x 91KB = 2.27MB (L2-resident per XCD).
template<int NT>
__device__ __forceinline__ void kb6_work(const _Float16 (*__restrict__ cS)[CSTR],
                                         float (*__restrict__ pRed)[128],
                                         const ush* __restrict__ Tp,
                                         int t0, int kq, int lane)
{
    const int cl = lane & 15, rg = lane >> 4;

    // consume weights (k-independent): cval[it][bt][r] = C[b][i]
    float cval[NT][8][4];
    #pragma unroll
    for (int it = 0; it < NT; ++it)
        #pragma unroll
        for (int bt = 0; bt < 8; ++bt)
            #pragma unroll
            for (int r = 0; r < 4; ++r)
                cval[it][bt][r] = (float)cS[bt * 16 + cl][(t0 + it) * 16 + rg * 4 + r];

    for (int kk = 0; kk < KPQ; ++kk) {
        const int k = kq * KPQ + kk;
        f32x4 acc[NT][8];
        #pragma unroll
        for (int it = 0; it < NT; ++it)
            #pragma unroll
            for (int bt = 0; bt < 8; ++bt)
                acc[it][bt] = (f32x4){0.f, 0.f, 0.f, 0.f};

        #pragma unroll
        for (int jc = 0; jc < NJC; ++jc) {
            f16x8 ah[NT];
            #pragma unroll
            for (int it = 0; it < NT; ++it)
                ah[it] = *(const f16x8*)(Tp +
                    ((((size_t)k * NIT + (t0 + it)) * NJC + jc) * 64 + lane) * 8);
            f16x8 bh[8];
            #pragma unroll
            for (int bt = 0; bt < 8; ++bt)
                bh[bt] = *(const f16x8*)&cS[bt * 16 + cl][jc * 32 + rg * 8];
            #pragma unroll
            for (int it = 0; it < NT; ++it)
                #pragma unroll
                for (int bt = 0; bt < 8; ++bt)
                    acc[it][bt] = __builtin_amdgcn_mfma_f32_16x16x32_f16(
                        ah[it], bh[bt], acc[it][bt], 0, 0, 0);
        }
        #pragma unroll
        for (int bt = 0; bt < 8; ++bt) {
            float v = 0.f;
            #pragma unroll
            for (int it = 0; it < NT; ++it)
                #pragma unroll
                for (int r = 0; r < 4; ++r)
                    v += acc[it][bt][r] * cval[it][bt][r];
            v += __shfl_xor(v, 16);
            v += __shfl_xor(v, 32);
            if (lane < 16) atomicAdd(&pRed[kk][bt * 16 + cl], v);
        }
    }
}

__global__ __launch_bounds__(512, 2) void kB6(const float* __restrict__ cat,
                                              const ush* __restrict__ Tp,
                                              const float* __restrict__ clb,
                                              float* __restrict__ cv)
{
    __shared__ _Float16 cS[128][CSTR];
    __shared__ float pRed[KPQ][128];
    const int tid = threadIdx.x;
    const int bid = blockIdx.x;
    // XCD-aware: both blocks/CU on an XCD share the same k-quarter
    const int kq = (bid >> 1) & 3;
    const int b0 = (((bid >> 3) << 1) | (bid & 1)) * 128;
    const int lane = tid & 63, w = tid >> 6;

    for (int idx = tid; idx < 128 * CSTR; idx += 512) {
        int r = idx / CSTR, c = idx - r * CSTR;
        float v = 0.f;
        if (c < 200) v = cat[(size_t)(b0 + r) * TD2 + c];
        else if (c == 200) v = 1.f;            // clW row weight
        cS[r][c] = (_Float16)v;
    }
    for (int idx = tid; idx < KPQ * 128; idx += 512) ((float*)pRed)[idx] = 0.f;
    __syncthreads();

    if (w < 5) kb6_work<2>(cS, pRed, Tp, 2 * w, kq, lane);
    else       kb6_work<1>(cS, pRed, Tp, 10 + (w - 5), kq, lane);
    __syncthreads();

    for (int idx = tid; idx < KPQ * 128; idx += 512) {
        int kk = idx >> 7, b = idx & 127;
        int k = kq * KPQ + kk;
        cv[(size_t)k * BATCH + b0 + b] = leaky(pRed[kk][b] + clb[k]);
    }
}

// ---------------- Kernel B4 (fallback if ws too small): packed-f32 trilinear --------
__global__ __launch_bounds__(512, 6) void kB4(const float* __restrict__ cat,
                                              const float* __restrict__ compT,
                                              const float* __restrict__ clW,
                                              const float* __restrict__ clb,
                                              float* __restrict__ cv)
{
    __shared__ float cS[64][201];
    const int tid = threadIdx.x;
    const int b0 = blockIdx.x * 64;
    const int lane = tid & 63;
    const int wid = tid >> 6;

    {
        int r = tid / TD2;
        int c = tid - r * TD2;
        for (int i = tid; i < 64 * TD2; i += 512) {
            cS[r][c] = cat[(size_t)(b0 + r) * TD2 + c];
            c += 112;
            if (c >= TD2) { c -= TD2; r += 3; } else { r += 2; }
        }
    }
    __syncthreads();

    int k = blockIdx.y * 8 + wid;
    if (k >= TDIM) return;
    k = __builtin_amdgcn_readfirstlane(k);

    const float* T = compT + (size_t)k * (TD2 * TD2);
    float s = 0.f;
    for (int ch = 0; ch < 4; ++ch) {
        const int c0 = ch * 50;
        f32x2 cj2[25];
        #pragma unroll
        for (int j = 0; j < 25; ++j) {
            f32x2 c2; c2.x = cS[lane][c0 + 2 * j]; c2.y = cS[lane][c0 + 2 * j + 1];
            cj2[j] = c2;
        }
        for (int i = 0; i < TD2; ++i) {
            const f32x2* T2 = (const f32x2*)(T + (size_t)i * TD2 + c0);
            f32x2 trow[25];
            #pragma unroll
            for (int j = 0; j < 25; ++j) trow[j] = T2[j];
            f32x2 u2; u2.x = 0.f; u2.y = 0.f;
            #pragma unroll
            for (int j = 0; j < 25; ++j) {
                asm("v_pk_fma_f32 %0, %1, %2, %0"
                    : "+v"(u2) : "s"(trow[j]), "v"(cj2[j]));
            }
            s += cS[lane][i] * (u2.x + u2.y);
        }
    }
    float t2 = 0.f;
    const float* W = clW + (size_t)k * TD2;
    for (int j = 0; j < TD2; ++j) t2 += W[j] * cS[lane][j];
    cv[(size_t)k * BATCH + b0 + lane] = leaky(s + t2 + clb[k]);
}

// ---------------- Kernel C: l1 + l2 -> unnormalized out (f32) + ssq ----------------
// reads cv in [k][b] layout.
__global__ __launch_bounds__(256) void kC(const float* __restrict__ cv,
                                          const float* __restrict__ l1W,
                                          const float* __restrict__ l1b,
                                          const float* __restrict__ l2W,
                                          const float* __restrict__ l2b,
                                          float* __restrict__ out,
                                          float* __restrict__ ssqg)
{
    __shared__ ush hS[32 * 528];     // 33792 B
    __shared__ float w2F[8 * 516];   // 16512 B (cv tile aliased here first)
    const int tid = threadIdx.x;
    const int b0 = blockIdx.x * 32;

    float* cvS = w2F;  // 3200 floats
    for (int i = tid; i < 3200; i += 256) {
        int k = i >> 5, bl = i & 31;
        cvS[bl * TDIM + k] = cv[(size_t)k * BATCH + b0 + bl];
    }
    __syncthreads();
    for (int o = tid; o < 32 * HDIM; o += 256) {
        int bl = o & 31, e = o >> 5;
        const float* cr = &cvS[bl * TDIM];
        const float* wr = &l1W[e * TDIM];
        float s = 0.f;
        for (int t = 0; t < TDIM; t += 4) {
            float4 w4 = *(const float4*)&wr[t];
            float4 c4 = *(const float4*)&cr[t];
            s += w4.x * c4.x + w4.y * c4.y + w4.z * c4.z + w4.w * c4.w;
        }
        s = leaky(s + l1b[e]);
        hS[bl * 528 + e] = f2bf(s);
    }
    __syncthreads();

    const int b = tid >> 3, el = tid & 7;
    float ssq = 0.f;
    for (int ec = 0; ec < 128; ++ec) {
        {
            const float* src = l2W + (size_t)ec * 8 * HDIM;
            for (int i = tid; i < 1024; i += 256) {
                int r = i >> 7, c4 = (i & 127) * 4;
                *(float4*)&w2F[r * 516 + c4] = *(const float4*)&src[r * HDIM + c4];
            }
        }
        __syncthreads();
        {
            const ush* hr = &hS[b * 528];
            const float* wr2 = &w2F[el * 516];
            float s = 0.f;
            for (int j = 0; j < HDIM; j += 8) {
                uint4 hv = *(const uint4*)&hr[j];
                float4 w0 = *(const float4*)&wr2[j];
                float4 w1 = *(const float4*)&wr2[j + 4];
                float2 h0 = bf2x2(hv.x), h1 = bf2x2(hv.y), h2 = bf2x2(hv.z), h3 = bf2x2(hv.w);
                s += h0.x * w0.x + h0.y * w0.y + h1.x * w0.z + h1.y * w0.w
                   + h2.x * w1.x + h2.y * w1.y + h3.x * w1.z + h3.y * w1.w;
            }
            int eg = ec * 8 + el;
            float v = s + l2b[eg];
            out[(size_t)(b0 + b) * ESIZE + eg] = v;
            ssq += v * v;
        }
        __syncthreads();
    }
    ssq += __shfl_xor(ssq, 1);
    ssq += __shfl_xor(ssq, 2);
    ssq += __shfl_xor(ssq, 4);
    if (el == 0) ssqg[b0 + b] = ssq;
}

// ---------------- Kernel D: normalize f32 rows in place ----------------
__global__ __launch_bounds__(256) void kD(float* __restrict__ out,
                                          const float* __restrict__ ssqg)
{
    const int tid = threadIdx.x;
    const int row = blockIdx.x * 2 + (tid >> 7);
    const int col = (tid & 127) * 8;
    const float r = rsqrtf(ssqg[row]);
    float* p = out + (size_t)row * ESIZE + col;
    float4 v0 = *(float4*)p;
    float4 v1 = *(float4*)(p + 4);
    v0.x *= r; v0.y *= r; v0.z *= r; v0.w *= r;
    v1.x *= r; v1.y *= r; v1.z *= r; v1.w *= r;
    *(float4*)p = v0;
    *(float4*)(p + 4) = v1;
}

extern "C" void kernel_launch(void* const* d_in, const int* in_sizes, int n_in,
                              void* d_out, int out_size, void* d_ws, size_t ws_size,
                              hipStream_t stream) {
    const int*   x    = (const int*)d_in[0];
    const float* eW   = (const float*)d_in[2];
    const float* pdW  = (const float*)d_in[3];
    const float* pdb  = (const float*)d_in[4];
    const float* cT   = (const float*)d_in[5];
    const float* clW  = (const float*)d_in[6];
    const float* clb  = (const float*)d_in[7];
    const float* l1W  = (const float*)d_in[8];
    const float* l1b  = (const float*)d_in[9];
    const float* l2W  = (const float*)d_in[10];
    const float* l2b  = (const float*)d_in[11];
    float* out = (float*)d_out;

    // workspace layout
    const size_t catN = (size_t)BATCH * TD2;                 // f32
    const size_t cvN  = (size_t)BATCH * TDIM;                // f32
    const size_t ssqN = (size_t)BATCH;                       // f32
    const size_t tpN  = (size_t)TDIM * NIT * NJC * 64 * 8;   // ush (fp16 T')

    float* cat  = (float*)d_ws;
    float* cv   = cat + catN;
    float* ssqg = cv + cvN;
    ush*   Tp   = (ush*)(ssqg + ssqN);

    const size_t need = (catN + cvN + ssqN) * 4 + tpN * 2;

    kA3<<<dim3(BATCH / 16), dim3(256), 0, stream>>>(x, eW, pdW, pdb, cat);
    if (ws_size >= need) {
        kT <<<dim3(TDIM, NIT), dim3(448), 0, stream>>>(cT, clW, Tp);
        kB6<<<dim3(512), dim3(512), 0, stream>>>(cat, Tp, clb, cv);
    } else {
        kB4<<<dim3(BATCH / 64, 13), dim3(512), 0, stream>>>(cat, cT, clW, clb, cv);
    }
    kC<<<dim3(512), dim3(256), 0, stream>>>(cv, l1W, l1b, l2W, l2b, out, ssqg);
    kD<<<dim3(8192), dim3(256), 0, stream>>>(out, ssqg);
}

// Round 6
// 846.233 us; speedup vs baseline: 17.4381x; 3.5654x over previous
//
#include <hip/hip_runtime.h>
#include <hip/hip_bf16.h>

#define BATCH 16384
#define WDIM 300
#define TDIM 100
#define TD2 200
#define HDIM 512
#define ESIZE 1024

// fp16 MFMA trilinear geometry
#define NIT 13            // i-tiles of 16: 208 = 200 real + clW row + pad
#define NJC 7             // j-chunks of 32: 224 = 200 real + pad
#define CSTR 232          // LDS C row stride (halves): 464B, 16B-mult, 2-way banks
// kC geometry
#define CVSTR 136         // cvS stride (halves): 272B = 16B-mult, 2-way banks
#define HSTR 520          // hS stride (halves): 1040B = 16B-mult, 2-way banks

typedef unsigned short ush;
typedef float f32x2 __attribute__((ext_vector_type(2)));
typedef float f32x4 __attribute__((ext_vector_type(4)));
typedef _Float16 f16x8 __attribute__((ext_vector_type(8)));
typedef _Float16 f16x4 __attribute__((ext_vector_type(4)));

__device__ __forceinline__ float bf2f(ush u) {
    union { unsigned int i; float f; } v; v.i = ((unsigned int)u) << 16; return v.f;
}
__device__ __forceinline__ float2 bf2x2(unsigned int w) {
    union { unsigned int i; float f; } a, b;
    a.i = w << 16; b.i = w & 0xffff0000u;
    return make_float2(a.f, b.f);
}
__device__ __forceinline__ ush f2bf(float f) {
    union { float f; unsigned int i; } v; v.f = f;
    unsigned int x = v.i;
    return (ush)((x + 0x7fffu + ((x >> 16) & 1u)) >> 16);
}
__device__ __forceinline__ float leaky(float v) { return v >= 0.f ? v : 0.1f * v; }

// ---------------- Kernel A3: LDS-staged, coalesced embed/projdown ----------------
__global__ __launch_bounds__(256) void kA3(const int* __restrict__ x,
                                           const float* __restrict__ eW,
                                           const float* __restrict__ pdW,
                                           const float* __restrict__ pdb,
                                           float* __restrict__ cat)
{
    __shared__ float eS[32][308];
    __shared__ float pS[20][308];
    __shared__ int idxS[32];
    const int tid = threadIdx.x;
    const int lane = tid & 63, wv = tid >> 6;
    const int b0 = blockIdx.x * 16;

    if (tid < 32) idxS[tid] = x[b0 * 2 + tid];
    __syncthreads();

    for (int r = wv; r < 32; r += 4) {
        const float4* src = (const float4*)(eW + (size_t)idxS[r] * WDIM);
        for (int d = lane; d < 75; d += 64) *(float4*)&eS[r][d * 4] = src[d];
    }

    const int r = tid >> 3, tl = tid & 7;
    const int t2ok = (tl + 16) < 20;
    const int b = b0 + (r >> 1), h = r & 1;

    for (int tc = 0; tc < 5; ++tc) {
        __syncthreads();
        for (int i = tid; i < 1500; i += 256) {
            int rr = i / 75, d = i - rr * 75;
            *(float4*)&pS[rr][d * 4] =
                *(const float4*)&pdW[(size_t)(tc * 20 + rr) * WDIM + d * 4];
        }
        __syncthreads();

        float a0 = 0.f, a1 = 0.f, a2 = 0.f;
        const int t2i = t2ok ? (tl + 16) : 0;
        for (int d = 0; d < 75; ++d) {
            float4 e4 = *(const float4*)&eS[r][d * 4];
            float4 p0 = *(const float4*)&pS[tl][d * 4];
            float4 p1 = *(const float4*)&pS[tl + 8][d * 4];
            float4 p2 = *(const float4*)&pS[t2i][d * 4];
            a0 += e4.x * p0.x + e4.y * p0.y + e4.z * p0.z + e4.w * p0.w;
            a1 += e4.x * p1.x + e4.y * p1.y + e4.z * p1.z + e4.w * p1.w;
            a2 += e4.x * p2.x + e4.y * p2.y + e4.z * p2.z + e4.w * p2.w;
        }
        {
            int t = tc * 20 + tl;
            cat[(size_t)b * TD2 + h * 100 + t] = leaky(a0 + pdb[t]);
            t += 8;
            cat[(size_t)b * TD2 + h * 100 + t] = leaky(a1 + pdb[t]);
            if (t2ok) {
                t += 8;
                cat[(size_t)b * TD2 + h * 100 + t] = leaky(a2 + pdb[t]);
            }
        }
    }
}

// ---------------- Kernel T: build fragment-ordered fp16 T' ----------------
__global__ __launch_bounds__(448) void kT(const float* __restrict__ compT,
                                          const float* __restrict__ clW,
                                          ush* __restrict__ Tp)
{
    const int k = blockIdx.x, it = blockIdx.y;
    const int jc = threadIdx.x >> 6, lane = threadIdx.x & 63;
    const int i = it * 16 + (lane & 15);
    const int j0 = jc * 32 + (lane >> 4) * 8;
    ush vals[8];
    #pragma unroll
    for (int e = 0; e < 8; ++e) {
        int j = j0 + e;
        float v = 0.f;
        if (j < 200) {
            if (i < 200) v = compT[((size_t)k * 200 + i) * 200 + j];
            else if (i == 200) v = clW[(size_t)k * 200 + j];
        }
        union { _Float16 h; ush u; } cvt; cvt.h = (_Float16)v; vals[e] = cvt.u;
    }
    size_t o = (((size_t)k * NIT + it) * NJC + jc) * 64 + lane;   // 16B units
    ((uint4*)Tp)[o] = *(const uint4*)vals;
}

// ---------------- Kernel W: convert l1W/l2W to fp16 (l1 padded K->128) ----------
__global__ __launch_bounds__(256) void kW(const float* __restrict__ l1W,
                                          const float* __restrict__ l2W,
                                          ush* __restrict__ l1p,
                                          ush* __restrict__ l2p)
{
    const int idx = blockIdx.x * 256 + threadIdx.x;
    union { _Float16 h; ush u; } cvt;
    if (idx < HDIM * 128) {
        int r = idx >> 7, c = idx & 127;
        cvt.h = (_Float16)(c < TDIM ? l1W[r * TDIM + c] : 0.f);
        l1p[idx] = cvt.u;
    } else {
        int j = idx - HDIM * 128;
        cvt.h = (_Float16)l2W[j];
        l2p[j] = cvt.u;
    }
}

// ---------------- Kernel B7: fp16 MFMA trilinear, temporal-L2 k-sweep ----------
// grid 256 (64 batch rows each, 1 block/CU), block 512 = 8 waves.
// NO k-split: every block loops all 100 k in the SAME order -> all CUs share the
// current ~91KB/k T-window in every XCD's L2 (no XCD-placement assumption; slack
// ~43 k-values of drift). LLC traffic = 8 XCD x 9.3MB = 74MB total.
// Per k: waves compute partial row-dots, LDS atomic-reduce (double-buffered
// pRed, 1 barrier/k), write cv[k][b] directly.
template<int NT>
__device__ __forceinline__ void kb7_work(const _Float16 (*__restrict__ cS)[CSTR],
                                         float (*__restrict__ pRed)[64],
                                         const ush* __restrict__ Tp,
                                         const float* __restrict__ clb,
                                         float* __restrict__ cv,
                                         int t0, int b0, int lane, int tid)
{
    const int cl = lane & 15, rg = lane >> 4;

    float cval[NT][4][4];
    #pragma unroll
    for (int it = 0; it < NT; ++it)
        #pragma unroll
        for (int bt = 0; bt < 4; ++bt)
            #pragma unroll
            for (int r = 0; r < 4; ++r)
                cval[it][bt][r] = (float)cS[bt * 16 + cl][(t0 + it) * 16 + rg * 4 + r];

    for (int k = 0; k < TDIM; ++k) {
        const int p = k & 1;
        f32x4 acc[NT][4];
        #pragma unroll
        for (int it = 0; it < NT; ++it)
            #pragma unroll
            for (int bt = 0; bt < 4; ++bt)
                acc[it][bt] = (f32x4){0.f, 0.f, 0.f, 0.f};

        #pragma unroll
        for (int jc = 0; jc < NJC; ++jc) {
            f16x8 ah[NT];
            #pragma unroll
            for (int it = 0; it < NT; ++it)
                ah[it] = *(const f16x8*)(Tp +
                    ((((size_t)k * NIT + (t0 + it)) * NJC + jc) * 64 + lane) * 8);
            f16x8 bh[4];
            #pragma unroll
            for (int bt = 0; bt < 4; ++bt)
                bh[bt] = *(const f16x8*)&cS[bt * 16 + cl][jc * 32 + rg * 8];
            #pragma unroll
            for (int it = 0; it < NT; ++it)
                #pragma unroll
                for (int bt = 0; bt < 4; ++bt)
                    acc[it][bt] = __builtin_amdgcn_mfma_f32_16x16x32_f16(
                        ah[it], bh[bt], acc[it][bt], 0, 0, 0);
        }
        #pragma unroll
        for (int bt = 0; bt < 4; ++bt) {
            float v = 0.f;
            #pragma unroll
            for (int it = 0; it < NT; ++it)
                #pragma unroll
                for (int r = 0; r < 4; ++r)
                    v += acc[it][bt][r] * cval[it][bt][r];
            v += __shfl_xor(v, 16);
            v += __shfl_xor(v, 32);
            if (lane < 16) atomicAdd(&pRed[p][bt * 16 + lane], v);
        }
        __syncthreads();
        if (tid < 64) {
            float s = pRed[p][tid];
            pRed[p][tid] = 0.f;                 // re-zero for k+2 (ordered by k+1 barrier)
            cv[(size_t)k * BATCH + b0 + tid] = leaky(s + clb[k]);
        }
    }
}

__global__ __launch_bounds__(512, 2) void kB7(const float* __restrict__ cat,
                                              const ush* __restrict__ Tp,
                                              const float* __restrict__ clb,
                                              float* __restrict__ cv)
{
    __shared__ _Float16 cS[64][CSTR];   // 29.7 KB
    __shared__ float pRed[2][64];
    const int tid = threadIdx.x;
    const int b0 = blockIdx.x * 64;
    const int lane = tid & 63, w = tid >> 6;

    for (int idx = tid; idx < 64 * CSTR; idx += 512) {
        int r = idx / CSTR, c = idx - r * CSTR;
        float v = 0.f;
        if (c < 200) v = cat[(size_t)(b0 + r) * TD2 + c];
        else if (c == 200) v = 1.f;            // clW row weight
        cS[r][c] = (_Float16)v;
    }
    if (tid < 128) ((float*)pRed)[tid] = 0.f;
    __syncthreads();

    if (w < 5) kb7_work<2>(cS, pRed, Tp, clb, cv, 2 * w, b0, lane, tid);
    else       kb7_work<1>(cS, pRed, Tp, clb, cv, 10 + (w - 5), b0, lane, tid);
}

// ---------------- Kernel C1: cv -> h fp16 via MFMA (l1 + leaky) ----------------
// grid 256 (64 b-rows), block 512 = 8 waves. cvS [64][136] fp16 (K pad 128).
__global__ __launch_bounds__(512, 2) void kC1(const float* __restrict__ cv,
                                              const ush* __restrict__ l1p,
                                              const float* __restrict__ l1b,
                                              ush* __restrict__ h)
{
    __shared__ _Float16 cvS[64][CVSTR];
    const int tid = threadIdx.x;
    const int b0 = blockIdx.x * 64;
    const int lane = tid & 63, w = tid >> 6;
    const int cl = lane & 15, rg = lane >> 4;

    for (int k0 = 0; k0 < 128; k0 += 8) {
        int k = k0 + (w);
        int bl = lane;
        float v = (k < TDIM) ? cv[(size_t)k * BATCH + b0 + bl] : 0.f;
        cvS[bl][k] = (_Float16)v;
    }
    __syncthreads();

    for (int e8 = 0; e8 < 4; ++e8) {
        const int et = w * 4 + e8;
        f32x4 acc[4];
        #pragma unroll
        for (int bt = 0; bt < 4; ++bt) acc[bt] = (f32x4){0.f, 0.f, 0.f, 0.f};
        #pragma unroll
        for (int kc = 0; kc < 4; ++kc) {
            f16x8 a = *(const f16x8*)((const _Float16*)l1p +
                       (size_t)(et * 16 + cl) * 128 + kc * 32 + rg * 8);
            #pragma unroll
            for (int bt = 0; bt < 4; ++bt) {
                f16x8 b = *(const f16x8*)&cvS[bt * 16 + cl][kc * 32 + rg * 8];
                acc[bt] = __builtin_amdgcn_mfma_f32_16x16x32_f16(a, b, acc[bt], 0, 0, 0);
            }
        }
        float4 bias = *(const float4*)&l1b[et * 16 + rg * 4];
        #pragma unroll
        for (int bt = 0; bt < 4; ++bt) {
            f16x4 hv;
            hv[0] = (_Float16)leaky(acc[bt][0] + bias.x);
            hv[1] = (_Float16)leaky(acc[bt][1] + bias.y);
            hv[2] = (_Float16)leaky(acc[bt][2] + bias.z);
            hv[3] = (_Float16)leaky(acc[bt][3] + bias.w);
            *(f16x4*)((_Float16*)h + (size_t)(b0 + bt * 16 + cl) * HDIM
                      + et * 16 + rg * 4) = hv;
        }
    }
}

// ---------------- Kernel C2: h (fp16) x l2W^T via MFMA -> out f32 + ssq --------
// grid 256 (64 b-rows), block 512 = 8 waves; each wave owns 128 e-cols.
// hS [64][520] fp16 (66.6KB, 2-way banks); A (l2p fp16, 1MB) L2-resident.
__global__ __launch_bounds__(512, 2) void kC2(const ush* __restrict__ h,
                                              const ush* __restrict__ l2p,
                                              const float* __restrict__ l2b,
                                              float* __restrict__ out,
                                              float* __restrict__ ssqg)
{
    __shared__ _Float16 hS[64][HSTR];
    __shared__ float ssqS[64];
    const int tid = threadIdx.x;
    const int b0 = blockIdx.x * 64;
    const int lane = tid & 63, w = tid >> 6;
    const int cl = lane & 15, rg = lane >> 4;

    for (int it = 0; it < 8; ++it) {
        int idx = it * 512 + tid;
        int row = idx >> 6, c8 = (idx & 63) * 8;
        *(uint4*)&hS[row][c8] = *(const uint4*)(h + (size_t)(b0 + row) * HDIM + c8);
    }
    if (tid < 64) ssqS[tid] = 0.f;
    __syncthreads();

    float ssqp[4] = {0.f, 0.f, 0.f, 0.f};
    for (int e8 = 0; e8 < 8; ++e8) {
        const int et = w * 8 + e8;
        f32x4 acc[4];
        #pragma unroll
        for (int bt = 0; bt < 4; ++bt) acc[bt] = (f32x4){0.f, 0.f, 0.f, 0.f};
        #pragma unroll
        for (int kc = 0; kc < 16; ++kc) {
            f16x8 a = *(const f16x8*)((const _Float16*)l2p +
                       (size_t)(et * 16 + cl) * HDIM + kc * 32 + rg * 8);
            #pragma unroll
            for (int bt = 0; bt < 4; ++bt) {
                f16x8 b = *(const f16x8*)&hS[bt * 16 + cl][kc * 32 + rg * 8];
                acc[bt] = __builtin_amdgcn_mfma_f32_16x16x32_f16(a, b, acc[bt], 0, 0, 0);
            }
        }
        float4 bias = *(const float4*)&l2b[et * 16 + rg * 4];
        #pragma unroll
        for (int bt = 0; bt < 4; ++bt) {
            float4 o;
            o.x = acc[bt][0] + bias.x;
            o.y = acc[bt][1] + bias.y;
            o.z = acc[bt][2] + bias.z;
            o.w = acc[bt][3] + bias.w;
            ssqp[bt] += o.x * o.x + o.y * o.y + o.z * o.z + o.w * o.w;
            *(float4*)&out[(size_t)(b0 + bt * 16 + cl) * ESIZE + et * 16 + rg * 4] = o;
        }
    }
    #pragma unroll
    for (int bt = 0; bt < 4; ++bt) {
        float s = ssqp[bt];
        s += __shfl_xor(s, 16);
        s += __shfl_xor(s, 32);
        if (lane < 16) atomicAdd(&ssqS[bt * 16 + lane], s);
    }
    __syncthreads();
    if (tid < 64) ssqg[b0 + tid] = ssqS[tid];
}

// ---------------- Kernel B4 (fallback): packed-f32 trilinear -> cv[k][b] -------
__global__ __launch_bounds__(512, 6) void kB4(const float* __restrict__ cat,
                                              const float* __restrict__ compT,
                                              const float* __restrict__ clW,
                                              const float* __restrict__ clb,
                                              float* __restrict__ cv)
{
    __shared__ float cS[64][201];
    const int tid = threadIdx.x;
    const int b0 = blockIdx.x * 64;
    const int lane = tid & 63;
    const int wid = tid >> 6;

    {
        int r = tid / TD2;
        int c = tid - r * TD2;
        for (int i = tid; i < 64 * TD2; i += 512) {
            cS[r][c] = cat[(size_t)(b0 + r) * TD2 + c];
            c += 112;
            if (c >= TD2) { c -= TD2; r += 3; } else { r += 2; }
        }
    }
    __syncthreads();

    int k = blockIdx.y * 8 + wid;
    if (k >= TDIM) return;
    k = __builtin_amdgcn_readfirstlane(k);

    const float* T = compT + (size_t)k * (TD2 * TD2);
    float s = 0.f;
    for (int ch = 0; ch < 4; ++ch) {
        const int c0 = ch * 50;
        f32x2 cj2[25];
        #pragma unroll
        for (int j = 0; j < 25; ++j) {
            f32x2 c2; c2.x = cS[lane][c0 + 2 * j]; c2.y = cS[lane][c0 + 2 * j + 1];
            cj2[j] = c2;
        }
        for (int i = 0; i < TD2; ++i) {
            const f32x2* T2 = (const f32x2*)(T + (size_t)i * TD2 + c0);
            f32x2 trow[25];
            #pragma unroll
            for (int j = 0; j < 25; ++j) trow[j] = T2[j];
            f32x2 u2; u2.x = 0.f; u2.y = 0.f;
            #pragma unroll
            for (int j = 0; j < 25; ++j) {
                asm("v_pk_fma_f32 %0, %1, %2, %0"
                    : "+v"(u2) : "s"(trow[j]), "v"(cj2[j]));
            }
            s += cS[lane][i] * (u2.x + u2.y);
        }
    }
    float t2 = 0.f;
    const float* W = clW + (size_t)k * TD2;
    for (int j = 0; j < TD2; ++j) t2 += W[j] * cS[lane][j];
    cv[(size_t)k * BATCH + b0 + lane] = leaky(s + t2 + clb[k]);
}

// ---------------- Kernel Cf (fallback): f32 l1+l2 path, reads cv[k][b] ---------
__global__ __launch_bounds__(256) void kCf(const float* __restrict__ cv,
                                           const float* __restrict__ l1W,
                                           const float* __restrict__ l1b,
                                           const float* __restrict__ l2W,
                                           const float* __restrict__ l2b,
                                           float* __restrict__ out,
                                           float* __restrict__ ssqg)
{
    __shared__ ush hS[32 * 528];
    __shared__ float w2F[8 * 516];
    const int tid = threadIdx.x;
    const int b0 = blockIdx.x * 32;

    float* cvS = w2F;
    for (int i = tid; i < 3200; i += 256) {
        int k = i >> 5, bl = i & 31;
        cvS[bl * TDIM + k] = cv[(size_t)k * BATCH + b0 + bl];
    }
    __syncthreads();
    for (int o = tid; o < 32 * HDIM; o += 256) {
        int bl = o & 31, e = o >> 5;
        const float* cr = &cvS[bl * TDIM];
        const float* wr = &l1W[e * TDIM];
        float s = 0.f;
        for (int t = 0; t < TDIM; t += 4) {
            float4 w4 = *(const float4*)&wr[t];
            float4 c4 = *(const float4*)&cr[t];
            s += w4.x * c4.x + w4.y * c4.y + w4.z * c4.z + w4.w * c4.w;
        }
        s = leaky(s + l1b[e]);
        hS[bl * 528 + e] = f2bf(s);
    }
    __syncthreads();

    const int b = tid >> 3, el = tid & 7;
    float ssq = 0.f;
    for (int ec = 0; ec < 128; ++ec) {
        {
            const float* src = l2W + (size_t)ec * 8 * HDIM;
            for (int i = tid; i < 1024; i += 256) {
                int r = i >> 7, c4 = (i & 127) * 4;
                *(float4*)&w2F[r * 516 + c4] = *(const float4*)&src[r * HDIM + c4];
            }
        }
        __syncthreads();
        {
            const ush* hr = &hS[b * 528];
            const float* wr2 = &w2F[el * 516];
            float s = 0.f;
            for (int j = 0; j < HDIM; j += 8) {
                uint4 hv = *(const uint4*)&hr[j];
                float4 w0 = *(const float4*)&wr2[j];
                float4 w1 = *(const float4*)&wr2[j + 4];
                float2 h0 = bf2x2(hv.x), h1 = bf2x2(hv.y), h2 = bf2x2(hv.z), h3 = bf2x2(hv.w);
                s += h0.x * w0.x + h0.y * w0.y + h1.x * w0.z + h1.y * w0.w
                   + h2.x * w1.x + h2.y * w1.y + h3.x * w1.z + h3.y * w1.w;
            }
            int eg = ec * 8 + el;
            float v = s + l2b[eg];
            out[(size_t)(b0 + b) * ESIZE + eg] = v;
            ssq += v * v;
        }
        __syncthreads();
    }
    ssq += __shfl_xor(ssq, 1);
    ssq += __shfl_xor(ssq, 2);
    ssq += __shfl_xor(ssq, 4);
    if (el == 0) ssqg[b0 + b] = ssq;
}

// ---------------- Kernel D: normalize f32 rows in place ----------------
__global__ __launch_bounds__(256) void kD(float* __restrict__ out,
                                          const float* __restrict__ ssqg)
{
    const int tid = threadIdx.x;
    const int row = blockIdx.x * 2 + (tid >> 7);
    const int col = (tid & 127) * 8;
    const float r = rsqrtf(ssqg[row]);
    float* p = out + (size_t)row * ESIZE + col;
    float4 v0 = *(float4*)p;
    float4 v1 = *(float4*)(p + 4);
    v0.x *= r; v0.y *= r; v0.z *= r; v0.w *= r;
    v1.x *= r; v1.y *= r; v1.z *= r; v1.w *= r;
    *(float4*)p = v0;
    *(float4*)(p + 4) = v1;
}

extern "C" void kernel_launch(void* const* d_in, const int* in_sizes, int n_in,
                              void* d_out, int out_size, void* d_ws, size_t ws_size,
                              hipStream_t stream) {
    const int*   x    = (const int*)d_in[0];
    const float* eW   = (const float*)d_in[2];
    const float* pdW  = (const float*)d_in[3];
    const float* pdb  = (const float*)d_in[4];
    const float* cT   = (const float*)d_in[5];
    const float* clW  = (const float*)d_in[6];
    const float* clb  = (const float*)d_in[7];
    const float* l1W  = (const float*)d_in[8];
    const float* l1b  = (const float*)d_in[9];
    const float* l2W  = (const float*)d_in[10];
    const float* l2b  = (const float*)d_in[11];
    float* out = (float*)d_out;

    // workspace layout (all segments 16B-aligned by construction)
    const size_t catN = (size_t)BATCH * TD2;                 // f32
    const size_t cvN  = (size_t)BATCH * TDIM;                // f32
    const size_t ssqN = (size_t)BATCH;                       // f32
    const size_t tpN  = (size_t)TDIM * NIT * NJC * 64 * 8;   // ush
    const size_t l1pN = (size_t)HDIM * 128;                  // ush
    const size_t l2pN = (size_t)ESIZE * HDIM;                // ush
    const size_t hN   = (size_t)BATCH * HDIM;                // ush

    float* cat  = (float*)d_ws;
    float* cv   = cat + catN;
    float* ssqg = cv + cvN;
    ush*   Tp   = (ush*)(ssqg + ssqN);
    ush*   l1p  = Tp + tpN;
    ush*   l2p  = l1p + l1pN;
    ush*   hbuf = l2p + l2pN;

    const size_t need = (catN + cvN + ssqN) * 4 + (tpN + l1pN + l2pN + hN) * 2;

    kA3<<<dim3(BATCH / 16), dim3(256), 0, stream>>>(x, eW, pdW, pdb, cat);
    if (ws_size >= need) {
        kT <<<dim3(TDIM, NIT), dim3(448), 0, stream>>>(cT, clW, Tp);
        kW <<<dim3((HDIM * 128 + ESIZE * HDIM) / 256), dim3(256), 0, stream>>>(l1W, l2W, l1p, l2p);
        kB7<<<dim3(BATCH / 64), dim3(512), 0, stream>>>(cat, Tp, clb, cv);
        kC1<<<dim3(BATCH / 64), dim3(512), 0, stream>>>(cv, l1p, l1b, hbuf);
        kC2<<<dim3(BATCH / 64), dim3(512), 0, stream>>>(hbuf, l2p, l2b, out, ssqg);
    } else {
        kB4<<<dim3(BATCH / 64, 13), dim3(512), 0, stream>>>(cat, cT, clW, clb, cv);
        kCf<<<dim3(512), dim3(256), 0, stream>>>(cv, l1W, l1b, l2W, l2b, out, ssqg);
    }
    kD<<<dim3(8192), dim3(256), 0, stream>>>(out, ssqg);
}